// Round 3
// baseline (545.450 us; speedup 1.0000x reference)
//
#include <hip/hip_runtime.h>
#include <stdint.h>

// LSTM cell: gates = [x | h_prev] @ [W;U] + b ; B=131072, E=H=128
// GEMM M=131072, K=256, N=512 via 3-term bf16 split MFMA (hi*hi + hi*lo + lo*hi).
// R2: persistent blocks, double-buffered LDS, reg-pipelined B, rcp-based epilogue.

#define NB 131072
#define KDIM 256
#define NDIM 512
#define BM 64
#define TILES 8
#define GRID 256   // GRID * TILES * BM == NB

typedef __attribute__((ext_vector_type(4))) float f32x4;
typedef __attribute__((ext_vector_type(8))) short s16x8;

__device__ __forceinline__ float asf(unsigned u){ union{unsigned u;float f;}v; v.u=u; return v.f; }
__device__ __forceinline__ unsigned asu(float f){ union{float f;unsigned u;}v; v.f=f; return v.u; }

// round-to-nearest-even bf16, returned as rounded 32-bit pattern (bf16 = top 16 bits)
__device__ __forceinline__ unsigned rne(float f){
    unsigned u = asu(f);
    return u + 0x7FFFu + ((u >> 16) & 1u);
}
__device__ __forceinline__ unsigned short f2bf(float f){ return (unsigned short)(rne(f) >> 16); }
__device__ __forceinline__ float bf2f(unsigned short h){ return asf(((unsigned)h) << 16); }

// split a float4 into packed bf16-hi pair-words and bf16-lo pair-words
__device__ __forceinline__ void cvt4(f32x4 v, uint2 &hh, uint2 &ll){
    unsigned r0 = rne(v.x), r1 = rne(v.y), r2 = rne(v.z), r3 = rne(v.w);
    hh.x = (r0 >> 16) | (r1 & 0xFFFF0000u);
    hh.y = (r2 >> 16) | (r3 & 0xFFFF0000u);
    float l0 = v.x - asf(r0 & 0xFFFF0000u);
    float l1 = v.y - asf(r1 & 0xFFFF0000u);
    float l2 = v.z - asf(r2 & 0xFFFF0000u);
    float l3 = v.w - asf(r3 & 0xFFFF0000u);
    unsigned s0 = rne(l0), s1 = rne(l1), s2 = rne(l2), s3 = rne(l3);
    ll.x = (s0 >> 16) | (s1 & 0xFFFF0000u);
    ll.y = (s2 >> 16) | (s3 & 0xFFFF0000u);
}

__device__ __forceinline__ float sig_f(float g){
    return __builtin_amdgcn_rcpf(1.0f + __expf(-g));          // 1/(1+e^-g), rcp ~1ulp
}
__device__ __forceinline__ float tanh_f(float g){
    return 1.0f - 2.0f * __builtin_amdgcn_rcpf(__expf(2.0f * g) + 1.0f);  // inf-safe
}

// ---------------------------------------------------------------------------
// Prepass: pack W/U (fp32) into per-lane MFMA B-fragment order, bf16 hi/lo.
// frag (kf, jg) holds B[k = kf*32 + (lane>>4)*8 + e][j = jg*16 + (lane&15)]
// at ushort offset ((kf*32 + jg)*64 + lane)*8 + e.
// ---------------------------------------------------------------------------
__global__ void pack_weights(const float* __restrict__ Wi, const float* __restrict__ Ui,
                             const float* __restrict__ Wf, const float* __restrict__ Uf,
                             const float* __restrict__ Wo, const float* __restrict__ Uo,
                             const float* __restrict__ Wc, const float* __restrict__ Uc,
                             unsigned short* __restrict__ Bhi, unsigned short* __restrict__ Blo) {
    int tid = blockIdx.x * blockDim.x + threadIdx.x;   // 0 .. 16383
    if (tid >= 8 * 32 * 64) return;
    int lane = tid & 63;
    int jg   = (tid >> 6) & 31;
    int kf   = tid >> 11;

    int j  = jg * 16 + (lane & 15);    // 0..511
    int g  = j >> 7;
    int jj = j & 127;
    const float* W = (g == 0) ? Wi : (g == 1) ? Wf : (g == 2) ? Wo : Wc;
    const float* U = (g == 0) ? Ui : (g == 1) ? Uf : (g == 2) ? Uo : Uc;

    int k0 = kf * 32 + ((lane >> 4) << 3);
    s16x8 h8, l8;
    #pragma unroll
    for (int e = 0; e < 8; ++e) {
        int k = k0 + e;
        float v = (k < 128) ? W[k * 128 + jj] : U[(k - 128) * 128 + jj];
        unsigned short h = f2bf(v);
        float r = v - bf2f(h);
        h8[e] = (short)h;
        l8[e] = (short)f2bf(r);
    }
    size_t off = (size_t)tid * 8;
    *reinterpret_cast<s16x8*>(Bhi + off) = h8;
    *reinterpret_cast<s16x8*>(Blo + off) = l8;
}

// ---------------------------------------------------------------------------
// Persistent main kernel: 256 blocks x 8 tiles of 64 rows. 8 waves/block;
// wave w owns h-columns [w*16, w*16+16) for ALL 4 gates -> register epilogue.
// Double-buffered LDS: convert tile t+1 while computing tile t; loads for
// tile t+2 in flight across the whole compute phase.
// ---------------------------------------------------------------------------
__global__ __launch_bounds__(512, 2) void lstm_main(
        const float* __restrict__ x, const float* __restrict__ hprev,
        const float* __restrict__ cprev,
        const unsigned short* __restrict__ Bhi, const unsigned short* __restrict__ Blo,
        const float* __restrict__ bi, const float* __restrict__ bf_,
        const float* __restrict__ bo, const float* __restrict__ bc,
        float* __restrict__ hout, float* __restrict__ cout) {

    __shared__ unsigned short smem[2][2][BM * KDIM];   // [buf][hi/lo] = 128 KiB

    const int t    = threadIdx.x;
    const int lane = t & 63;
    const int w    = t >> 6;

    const int j = w * 16 + (lane & 15);                // this wave's h-column
    const float vbi = bi[j], vbf = bf_[j], vbo = bo[j], vbc = bc[j];

    // per-thread staging geometry: f4 = s*512 + t -> row = f4>>6 (const per s), k0 = (f4&63)*4
    f32x4 sreg[8];

    #define LOAD_A(tile_)                                                         \
        {   const int row0_ = (tile_) * BM;                                       \
            _Pragma("unroll")                                                     \
            for (int s = 0; s < 8; ++s) {                                         \
                int f4 = s * 512 + t;                                             \
                int row = f4 >> 6, k0 = (f4 & 63) * 4;                            \
                const float* src = (k0 < 128)                                     \
                    ? (x     + (size_t)(row0_ + row) * 128 + k0)                  \
                    : (hprev + (size_t)(row0_ + row) * 128 + (k0 - 128));         \
                sreg[s] = __builtin_nontemporal_load(                             \
                              reinterpret_cast<const f32x4*>(src));               \
            }                                                                     \
        }

    #define CONVERT_A(buf_)                                                       \
        {   char* hi_c = reinterpret_cast<char*>(&smem[(buf_)][0][0]);            \
            char* lo_c = reinterpret_cast<char*>(&smem[(buf_)][1][0]);            \
            _Pragma("unroll")                                                     \
            for (int s = 0; s < 8; ++s) {                                         \
                int f4 = s * 512 + t;                                             \
                int row = f4 >> 6, k0 = (f4 & 63) * 4;                            \
                uint2 hh, ll;                                                     \
                cvt4(sreg[s], hh, ll);                                            \
                int byte = (row * 512 + k0 * 2) ^ ((row & 7) << 4);               \
                *reinterpret_cast<uint2*>(hi_c + byte) = hh;                      \
                *reinterpret_cast<uint2*>(lo_c + byte) = ll;                      \
            }                                                                     \
        }

    const int tile0 = blockIdx.x * TILES;

    // ---- prologue ----
    LOAD_A(tile0);
    CONVERT_A(0);
    LOAD_A(tile0 + 1);
    __syncthreads();

    for (int it = 0; it < TILES; ++it) {
        const int cur = it & 1;

        if (it + 1 < TILES) CONVERT_A(cur ^ 1);        // tile it+1 (regs long since arrived)
        if (it + 2 < TILES) LOAD_A(tile0 + it + 2);    // in flight across this whole iter

        const int tile = tile0 + it;
        const int row0 = tile * BM;

        // c_prev prefetch for this tile (consumed in epilogue)
        float cp[4][4];
        #pragma unroll
        for (int m = 0; m < 4; ++m)
            #pragma unroll
            for (int r = 0; r < 4; ++r)
                cp[m][r] = __builtin_nontemporal_load(
                    cprev + (size_t)(row0 + m * 16 + ((lane >> 4) << 2) + r) * 128 + j);

        // ---- MFMA: K = 256 = 8 kf-steps, B double-buffered in regs ----
        f32x4 acc[4][4];
        #pragma unroll
        for (int m = 0; m < 4; ++m)
            #pragma unroll
            for (int g = 0; g < 4; ++g)
                acc[m][g] = (f32x4){0.f, 0.f, 0.f, 0.f};

        const char* hi_c = reinterpret_cast<const char*>(&smem[cur][0][0]);
        const char* lo_c = reinterpret_cast<const char*>(&smem[cur][1][0]);

        #define BOFF(kf_, g_) ((size_t)((((kf_) * 32 + (g_) * 8 + w) * 64 + lane)) * 8)

        s16x8 bh[2][4], bl[2][4];
        #pragma unroll
        for (int g = 0; g < 4; ++g) {
            bh[0][g] = *reinterpret_cast<const s16x8*>(Bhi + BOFF(0, g));
            bl[0][g] = *reinterpret_cast<const s16x8*>(Blo + BOFF(0, g));
        }

        #pragma unroll
        for (int kf = 0; kf < 8; ++kf) {
            const int c = kf & 1, n = c ^ 1;
            if (kf < 7) {
                #pragma unroll
                for (int g = 0; g < 4; ++g) {
                    bh[n][g] = *reinterpret_cast<const s16x8*>(Bhi + BOFF(kf + 1, g));
                    bl[n][g] = *reinterpret_cast<const s16x8*>(Blo + BOFF(kf + 1, g));
                }
            }
            #pragma unroll
            for (int m = 0; m < 4; ++m) {
                int row   = m * 16 + (lane & 15);
                int kbyte = kf * 64 + ((lane >> 4) << 4);
                int byte  = (row * 512 + kbyte) ^ ((row & 7) << 4);
                s16x8 af = *reinterpret_cast<const s16x8*>(hi_c + byte);
                s16x8 al = *reinterpret_cast<const s16x8*>(lo_c + byte);
                #pragma unroll
                for (int g = 0; g < 4; ++g)
                    acc[m][g] = __builtin_amdgcn_mfma_f32_16x16x32_bf16(af, bh[c][g], acc[m][g], 0, 0, 0);
                #pragma unroll
                for (int g = 0; g < 4; ++g)
                    acc[m][g] = __builtin_amdgcn_mfma_f32_16x16x32_bf16(af, bl[c][g], acc[m][g], 0, 0, 0);
                #pragma unroll
                for (int g = 0; g < 4; ++g)
                    acc[m][g] = __builtin_amdgcn_mfma_f32_16x16x32_bf16(al, bh[c][g], acc[m][g], 0, 0, 0);
            }
        }

        // ---- fused LSTM epilogue (C/D layout: col = lane&15, row = (lane>>4)*4 + r) ----
        #pragma unroll
        for (int m = 0; m < 4; ++m) {
            int rbase = row0 + m * 16 + ((lane >> 4) << 2);
            #pragma unroll
            for (int r = 0; r < 4; ++r) {
                size_t off = (size_t)(rbase + r) * 128 + j;
                float gi = acc[m][0][r] + vbi;
                float gf = acc[m][1][r] + vbf;
                float go = acc[m][2][r] + vbo;
                float gc = acc[m][3][r] + vbc;
                float iv = sig_f(gi);
                float fv = sig_f(gf);
                float ov = sig_f(go);
                float cc = tanh_f(gc);
                float cn = fv * cp[m][r] + iv * cc;
                float hn = ov * tanh_f(cn);
                __builtin_nontemporal_store(hn, hout + off);
                __builtin_nontemporal_store(cn, cout + off);
            }
        }

        __syncthreads();
    }
    #undef LOAD_A
    #undef CONVERT_A
    #undef BOFF
}

// ---------------------------------------------------------------------------
extern "C" void kernel_launch(void* const* d_in, const int* in_sizes, int n_in,
                              void* d_out, int out_size, void* d_ws, size_t ws_size,
                              hipStream_t stream) {
    const float* x  = (const float*)d_in[0];
    const float* hm = (const float*)d_in[1];
    const float* Wi = (const float*)d_in[2];
    const float* Ui = (const float*)d_in[3];
    const float* bi = (const float*)d_in[4];
    const float* Wf = (const float*)d_in[5];
    const float* Uf = (const float*)d_in[6];
    const float* bf = (const float*)d_in[7];
    const float* Wo = (const float*)d_in[8];
    const float* Uo = (const float*)d_in[9];
    const float* bo = (const float*)d_in[10];
    const float* Wc = (const float*)d_in[11];
    const float* Uc = (const float*)d_in[12];
    const float* bc = (const float*)d_in[13];

    const size_t BH = (size_t)NB * 128;
    const float* hprev = hm;
    const float* cprev = hm + BH;
    float* hout = (float*)d_out;
    float* cout = (float*)d_out + BH;

    unsigned short* Bhi = (unsigned short*)d_ws;              // 256 KiB
    unsigned short* Blo = Bhi + (size_t)KDIM * NDIM;          // 256 KiB

    pack_weights<<<64, 256, 0, stream>>>(Wi, Ui, Wf, Uf, Wo, Uo, Wc, Uc, Bhi, Blo);

    lstm_main<<<GRID, 512, 0, stream>>>(
        x, hprev, cprev, Bhi, Blo, bi, bf, bo, bc, hout, cout);
}